// Round 12
// baseline (141.437 us; speedup 1.0000x reference)
//
#include <hip/hip_runtime.h>

#define NN 1000
#define HEADS_ 4
#define DM 128
#define EE 64000
#define NTOT 4000
#define ETOT 68000
#define CAP 48     // bucket holds ALL edges per dst: deg ~ Poisson(16)+1, P(>=48) ~ 1e-11
#define EB 34      // edge-builder blocks appended to the h-GEMM dispatch

// ---------------------------------------------------------------------------
// k1 GEMM body: 64x64 tile, K=64, swizzle g = q ^ ((r>>2)&15), acc[4][4] --
// proven spill-free (R2/R5/R9, 60-84 VGPR).  Fused GAT score epilogue.
// ---------------------------------------------------------------------------
__device__ void gemm64_k1(float* As, float* Bs, int mi, int ni,
                          const float* __restrict__ x, const float* __restrict__ W,
                          float* __restrict__ hbuf, const float* __restrict__ att,
                          float* __restrict__ ssrc, float* __restrict__ sdst) {
  int tid = threadIdx.x;
  int m0 = mi * 64, n0 = ni * 64;
  int tx = tid & 15, ty = tid >> 4;
  const float4* A4 = (const float4*)x;   // [16000][16]
  const float4* W4 = (const float4*)W;   // [128][16]
  float acc[4][4] = {};

  __syncthreads();
  {
    int q = tid & 15, r0 = tid >> 4;
#pragma unroll
    for (int p = 0; p < 4; ++p) {  // A: 64 rows
      int r = r0 + p * 16;
      float4 v = A4[(size_t)(m0 + r) * 16 + q];
      *(float4*)&As[r * 64 + ((q ^ ((r >> 2) & 15)) << 2)] = v;
    }
#pragma unroll
    for (int p = 0; p < 4; ++p) {  // B: 64 rows
      int r = r0 + p * 16;
      float4 v = W4[(size_t)(n0 + r) * 16 + q];
      *(float4*)&Bs[r * 64 + ((q ^ ((r >> 2) & 15)) << 2)] = v;
    }
  }
  __syncthreads();
#pragma unroll 4
  for (int q = 0; q < 16; ++q) {
    float4 a[4], b[4];
    int sa = (q ^ ty) << 2;
    int sb = (q ^ tx) << 2;
#pragma unroll
    for (int i = 0; i < 4; ++i)
      a[i] = *(const float4*)&As[(ty * 4 + i) * 64 + sa];
#pragma unroll
    for (int j = 0; j < 4; ++j)
      b[j] = *(const float4*)&Bs[(tx * 4 + j) * 64 + sb];
#pragma unroll
    for (int i = 0; i < 4; ++i)
#pragma unroll
      for (int j = 0; j < 4; ++j)
        acc[i][j] += a[i].x * b[j].x + a[i].y * b[j].y
                   + a[i].z * b[j].z + a[i].w * b[j].w;
  }

  int nc = n0 + tx * 4;
#pragma unroll
  for (int i = 0; i < 4; ++i) {
    int m = m0 + ty * 4 + i;
    *(float4*)&hbuf[(size_t)m * DM + nc] =
        make_float4(acc[i][0], acc[i][1], acc[i][2], acc[i][3]);
  }

  if (m0 < NN) {  // fused GAT score epilogue (rows < 1000 only)
    int hsel = tx >> 3;
    int h = ni * 2 + hsel;
    int kb = (tx & 7) * 4;
    float a0[4], a1[4];
#pragma unroll
    for (int j = 0; j < 4; ++j) {
      a0[j] = att[h * 64 + kb + j];
      a1[j] = att[h * 64 + 32 + kb + j];
    }
#pragma unroll
    for (int i = 0; i < 4; ++i) {
      int m = m0 + ty * 4 + i;
      float p0 = 0.f, p1 = 0.f;
#pragma unroll
      for (int j = 0; j < 4; ++j) {
        float g = acc[i][j];
        float lr = g > 0.f ? g : 0.2f * g;
        p0 += a0[j] * lr;
        p1 += a1[j] * lr;
      }
      p0 += __shfl_xor(p0, 1, 16); p1 += __shfl_xor(p1, 1, 16);
      p0 += __shfl_xor(p0, 2, 16); p1 += __shfl_xor(p1, 2, 16);
      p0 += __shfl_xor(p0, 4, 16); p1 += __shfl_xor(p1, 4, 16);
      if ((tx & 7) == 0 && m < NN) {
        ssrc[m * HEADS_ + h] = p0;
        sdst[m * HEADS_ + h] = p1;
      }
    }
  }
}

// -------- K1: blocks 0..499 = h-GEMM (250 m-tiles x 2 n-tiles) + score
//              blocks 500..499+EB = bucket build    (R5/R9 proven)
__global__ __launch_bounds__(256) void k1_kernel(const float* __restrict__ x,
                                                 const float* __restrict__ W,
                                                 const float* __restrict__ att,
                                                 float* __restrict__ hbuf,
                                                 float* __restrict__ ssrc,
                                                 float* __restrict__ sdst,
                                                 const int* __restrict__ ei,
                                                 int* __restrict__ cnt,
                                                 int* __restrict__ elist) {
  __shared__ float smem[8192];
  int bid = blockIdx.x;
  if (bid < 500) {
    gemm64_k1(smem, smem + 4096, bid >> 1, bid & 1, x, W, hbuf, att, ssrc, sdst);
  } else {
    for (int e = (bid - 500) * 256 + threadIdx.x; e < ETOT; e += EB * 256) {
      int s, d;
      if (e < EE) { s = ei[e]; d = ei[EE + e]; }
      else { s = d = e - EE; }  // self loops
      int pos = atomicAdd(&cnt[d], 1);
      if (pos < CAP) elist[d * CAP + pos] = s;
    }
  }
}

// ---------------------------------------------------------------------------
// K2 (mega3): R9/R11-verified phase sequence at 512 THREADS (4 waves/SIMD).
// 500 blocks x 512 threads, 8 nodes/block, 49.6 KB LDS -> 2 blocks/CU =
// 16 waves/CU = 4 waves/SIMD (2x R11): the only lever that has ever moved
// this kernel class (R1->R2: 1->2 wv/SIMD = 73.6->54.3 us).
// Per-thread work halves: GEMM frag 4x2 (acc[3][4][2]); a-reads become pure
// wave-broadcast (ty = tid>>6 is wave-uniform); b-read swizzle unchanged and
// still bank-spread over all 8 groups.  Attention reduce = 16 lanes
// (shfl_xor 1/2/4/8 within head group tx>>4).  Phase A: 2 head-slices per
// thread (2 loads/edge).  Barrier/overlay order byte-equivalent to R11.
// LDS: As[32][132] | rg2[8192]: A{exs,srcs} -> B{Bs} -> D{Bs2};
//      aoS[32][132] overlays As (dead after B).
// ---------------------------------------------------------------------------
__global__ __launch_bounds__(512) void mega3_kernel(const int* __restrict__ cnt,
                                                    const int* __restrict__ elist,
                                                    const float* __restrict__ ssrc,
                                                    const float* __restrict__ sdst,
                                                    const float* __restrict__ hbuf,
                                                    const float* __restrict__ inw,
                                                    const float* __restrict__ inb,
                                                    const float* __restrict__ outw,
                                                    const float* __restrict__ outb,
                                                    const float* __restrict__ bias,
                                                    float* __restrict__ out) {
  __shared__ float smem[12416];          // 49,664 B
  float* As    = smem;                   // [32][132]
  float* rg2   = smem + 4224;            // 8192-float overlay region
  float* exsF  = rg2;                    // [8][48][4]
  int*   srcsI = (int*)(rg2 + 1536);     // [8][48]
  float* Bs    = rg2;                    // [128][64] (phase B)
  float* Bs2   = rg2;                    // [128][64] (phase D)
  float* aoS   = smem;                   // [32][132] (overlay on As)

  int tid = threadIdx.x;
  int g0n = blockIdx.x * 8;              // first node of tile

  // ---- phase A1: stage edges + exp(score per head): 64 threads/node ----
  {
    int ln = tid >> 6, t64 = tid & 63;
    int d = g0n + ln;
    int m = cnt[d]; if (m > CAP) m = CAP;
    float sd = (d < NN) ? sdst[d * HEADS_ + (t64 & 3)] : 0.f;  // uniform/ln
    for (int base = 0; base < m; base += 16) {
      int i = base + (t64 >> 2);
      if (i < m) {
        int s = elist[d * CAP + i];
        if ((t64 & 3) == 0) srcsI[ln * CAP + i] = s;
        float ss = (s < NN) ? ssrc[s * HEADS_ + (t64 & 3)] : 0.f;
        exsF[ln * 192 + i * 4 + (t64 & 3)] = __expf(ss + sd);  // shift-invariant
      }
    }
  }
  __syncthreads();

  // ---- phase A2: gather-aggregate h rows into As; 2 head-slices/thread ----
  {
    int r = tid >> 4, f = tid & 15;      // row in [0,32), f4-group in [0,16)
    int ln = r >> 2, v = r & 3;
    int d = g0n + ln, b = d / NN;
    int m = cnt[d]; if (m > CAP) m = CAP;
    int h_lo = f >> 3, h_hi = 2 + (f >> 3);
    const float* hbase = hbuf + ((size_t)(b * 4 + v) * NN) * DM + f * 4;
    float4 alo = make_float4(0.f, 0.f, 0.f, 0.f), ahi = alo;
    float dlo = 1e-16f, dhi = 1e-16f;
    int i = 0;
    for (; i + 4 <= m; i += 4) {
      float exl[4], exh[4]; unsigned sl[4]; const float* hrow[4];
#pragma unroll
      for (int u = 0; u < 4; ++u) {
        exl[u] = exsF[ln * 192 + (i + u) * 4 + h_lo];
        exh[u] = exsF[ln * 192 + (i + u) * 4 + h_hi];
        sl[u] = (unsigned)(srcsI[ln * CAP + i + u] - b * NN);
        unsigned sc = sl[u] < NN ? sl[u] : 0u;   // clamped always-valid addr
        hrow[u] = hbase + (size_t)sc * DM;
      }
      float4 hl[4], hh[4];
#pragma unroll
      for (int u = 0; u < 4; ++u) {              // 8 loads in flight
        hl[u] = *(const float4*)(hrow[u]);
        hh[u] = *(const float4*)(hrow[u] + 64);
      }
#pragma unroll
      for (int u = 0; u < 4; ++u) {
        dlo += exl[u]; dhi += exh[u];
        float wl = sl[u] < NN ? exl[u] : 0.f, wh = sl[u] < NN ? exh[u] : 0.f;
        alo.x += wl * hl[u].x; alo.y += wl * hl[u].y;
        alo.z += wl * hl[u].z; alo.w += wl * hl[u].w;
        ahi.x += wh * hh[u].x; ahi.y += wh * hh[u].y;
        ahi.z += wh * hh[u].z; ahi.w += wh * hh[u].w;
      }
    }
    for (; i < m; ++i) {
      float exl = exsF[ln * 192 + i * 4 + h_lo];
      float exh = exsF[ln * 192 + i * 4 + h_hi];
      unsigned sl = (unsigned)(srcsI[ln * CAP + i] - b * NN);
      unsigned sc = sl < NN ? sl : 0u;
      const float* hrow = hbase + (size_t)sc * DM;
      float4 hl = *(const float4*)(hrow);
      float4 hh = *(const float4*)(hrow + 64);
      dlo += exl; dhi += exh;
      float wl = sl < NN ? exl : 0.f, wh = sl < NN ? exh : 0.f;
      alo.x += wl * hl.x; alo.y += wl * hl.y; alo.z += wl * hl.z; alo.w += wl * hl.w;
      ahi.x += wh * hh.x; ahi.y += wh * hh.y; ahi.z += wh * hh.z; ahi.w += wh * hh.w;
    }
    float il = 1.f / dlo, ih = 1.f / dhi;
    *(float4*)&As[r * 132 +      f * 4] = make_float4(alo.x * il, alo.y * il, alo.z * il, alo.w * il);
    *(float4*)&As[r * 132 + 64 + f * 4] = make_float4(ahi.x * ih, ahi.y * ih, ahi.z * ih, ahi.w * ih);
  }
  __syncthreads();

  // ---- phase B: qkv GEMM, frag 4x2 (32 rows x 384 cols, K=128) ----
  int tx = tid & 63, ty = tid >> 6;      // col pair tx*2, node ty
  float acc[3][4][2] = {};
  {
    const float4* W4 = (const float4*)inw;   // [384][32]
#pragma unroll
    for (int c = 0; c < 2; ++c) {
#pragma unroll
      for (int ni = 0; ni < 3; ++ni) {
        __syncthreads();
        {
          int q = tid & 15, r0 = tid >> 4;   // r0 in [0,32)
#pragma unroll
          for (int p = 0; p < 4; ++p) {      // Bs: 128 weight rows
            int r = r0 + p * 32;
            float4 v = W4[(size_t)(ni * 128 + r) * 32 + c * 16 + q];
            *(float4*)&Bs[r * 64 + ((q ^ ((r >> 2) & 15)) << 2)] = v;
          }
        }
        __syncthreads();
#pragma unroll 4
        for (int q = 0; q < 16; ++q) {
          float4 a[4], b[2];
#pragma unroll
          for (int i = 0; i < 4; ++i)        // wave-broadcast (ty uniform)
            a[i] = *(const float4*)&As[(ty * 4 + i) * 132 + c * 64 + q * 4];
#pragma unroll
          for (int j = 0; j < 2; ++j) {
            int rn = tx * 2 + j;
            b[j] = *(const float4*)&Bs[rn * 64 + ((q ^ ((rn >> 2) & 15)) << 2)];
          }
#pragma unroll
          for (int i = 0; i < 4; ++i)
#pragma unroll
            for (int j = 0; j < 2; ++j)
              acc[ni][i][j] += a[i].x * b[j].x + a[i].y * b[j].y
                             + a[i].z * b[j].z + a[i].w * b[j].w;
        }
      }
    }
  }

  // ---- phase C: +inb, then attention entirely in registers ----
  // acc[p][v][j] = {q,k,v}[node ty][view v][col tx*2+j]; head = tx>>4.
#pragma unroll
  for (int ni = 0; ni < 3; ++ni) {
    float b0 = inb[ni * 128 + tx * 2], b1 = inb[ni * 128 + tx * 2 + 1];
#pragma unroll
    for (int i = 0; i < 4; ++i) { acc[ni][i][0] += b0; acc[ni][i][1] += b1; }
  }
  float S[4][4];
#pragma unroll
  for (int vq = 0; vq < 4; ++vq)
#pragma unroll
    for (int vk = 0; vk < 4; ++vk)
      S[vq][vk] = acc[0][vq][0] * acc[1][vk][0] + acc[0][vq][1] * acc[1][vk][1];
  // reduce over the head's 16 tx-lanes (lane = tx; xor 1/2/4/8 stays in head)
#pragma unroll
  for (int vq = 0; vq < 4; ++vq)
#pragma unroll
    for (int vk = 0; vk < 4; ++vk) {
      float s = S[vq][vk];
      s += __shfl_xor(s, 1);
      s += __shfl_xor(s, 2);
      s += __shfl_xor(s, 4);
      s += __shfl_xor(s, 8);
      S[vq][vk] = s * 0.17677669529663687f;  // 1/sqrt(32)
    }
#pragma unroll
  for (int vq = 0; vq < 4; ++vq) {  // softmax over vk (redundant x16)
    float mx = fmaxf(fmaxf(S[vq][0], S[vq][1]), fmaxf(S[vq][2], S[vq][3]));
    float e0 = __expf(S[vq][0] - mx), e1 = __expf(S[vq][1] - mx);
    float e2 = __expf(S[vq][2] - mx), e3 = __expf(S[vq][3] - mx);
    float inv = 1.f / (e0 + e1 + e2 + e3);
    S[vq][0] = e0 * inv; S[vq][1] = e1 * inv; S[vq][2] = e2 * inv; S[vq][3] = e3 * inv;
  }
  float ao0[4], ao1[4];
#pragma unroll
  for (int vq = 0; vq < 4; ++vq) {
    ao0[vq] = S[vq][0] * acc[2][0][0] + S[vq][1] * acc[2][1][0]
            + S[vq][2] * acc[2][2][0] + S[vq][3] * acc[2][3][0];
    ao1[vq] = S[vq][0] * acc[2][0][1] + S[vq][1] * acc[2][1][1]
            + S[vq][2] * acc[2][2][1] + S[vq][3] * acc[2][3][1];
  }
  __syncthreads();  // all As/Bs reads (phase B) complete before overlays
  {
#pragma unroll
    for (int vq = 0; vq < 4; ++vq) {
      float2 w2 = make_float2(ao0[vq], ao1[vq]);
      *(float2*)&aoS[(ty * 4 + vq) * 132 + tx * 2] = w2;
    }
  }

  // ---- phase D: out_proj 32x128 frag 4x2, K=128 (2 chunks); remap write ----
  float oc[4][2] = {};
  const float4* O4 = (const float4*)outw;  // [128][32]
#pragma unroll
  for (int c = 0; c < 2; ++c) {
    {
      int q = tid & 15, r0 = tid >> 4;
#pragma unroll
      for (int p = 0; p < 4; ++p) {        // Bs2: 128 outw rows
        int r = r0 + p * 32;
        float4 v = O4[(size_t)r * 32 + c * 16 + q];
        *(float4*)&Bs2[r * 64 + ((q ^ ((r >> 2) & 15)) << 2)] = v;
      }
    }
    __syncthreads();   // (first one also publishes aoS)
#pragma unroll 4
    for (int q = 0; q < 16; ++q) {
      float4 a[4], bq[2];
#pragma unroll
      for (int i = 0; i < 4; ++i)          // wave-broadcast
        a[i] = *(const float4*)&aoS[(ty * 4 + i) * 132 + c * 64 + q * 4];
#pragma unroll
      for (int j = 0; j < 2; ++j) {
        int rn = tx * 2 + j;
        bq[j] = *(const float4*)&Bs2[rn * 64 + ((q ^ ((rn >> 2) & 15)) << 2)];
      }
#pragma unroll
      for (int i = 0; i < 4; ++i)
#pragma unroll
        for (int j = 0; j < 2; ++j)
          oc[i][j] += a[i].x * bq[j].x + a[i].y * bq[j].y
                    + a[i].z * bq[j].z + a[i].w * bq[j].w;
    }
    __syncthreads();
  }

  {  // epilogue: +outb +bias, remap row (node,v) -> (b*4+v)*NN + n
    int nc = tx * 2;
    float o0 = outb[nc] + bias[nc], o1 = outb[nc + 1] + bias[nc + 1];
#pragma unroll
    for (int i = 0; i < 4; ++i) {
      int node = g0n + ty, vv = i;       // rows ty*4+i => node ty, view i
      int bg = node / NN, n = node - bg * NN;
      int om = (bg * 4 + vv) * NN + n;
      *(float2*)&out[(size_t)om * DM + nc] = make_float2(oc[i][0] + o0, oc[i][1] + o1);
    }
  }
}

extern "C" void kernel_launch(void* const* d_in, const int* in_sizes, int n_in,
                              void* d_out, int out_size, void* d_ws, size_t ws_size,
                              hipStream_t stream) {
  const float* x    = (const float*)d_in[0];
  const float* W    = (const float*)d_in[1];
  const float* att  = (const float*)d_in[2];
  const float* inw  = (const float*)d_in[3];
  const float* inb  = (const float*)d_in[4];
  const float* outw = (const float*)d_in[5];
  const float* outb = (const float*)d_in[6];
  const float* bias = (const float*)d_in[7];
  const int*   ei   = (const int*)d_in[8];
  float* out = (float*)d_out;

  float* ws = (float*)d_ws;
  float* hbuf  = ws;                       // 2,048,000  (b,v,n)-major h
  float* ssrc  = ws + 12500000;            // 16,000 (rows>=1000 never read)
  float* sdst  = ssrc + 16000;             // 16,000
  int*   cnt   = (int*)(sdst + 16000);     //  4,000
  int*   elist = cnt + 4000;               // 192,000 (4000 x CAP)

  // zero cnt only (score reads are predicated)
  hipMemsetAsync(cnt, 0, 4000 * sizeof(int), stream);

  k1_kernel<<<500 + EB, 256, 0, stream>>>(x, W, att, hbuf, ssrc, sdst, ei, cnt, elist);
  mega3_kernel<<<NTOT / 8, 512, 0, stream>>>(cnt, elist, ssrc, sdst, hbuf,
                                             inw, inb, outw, outb, bias, out);
}